// Round 1
// baseline (631.846 us; speedup 1.0000x reference)
//
#include <hip/hip_runtime.h>

#define RN 32768
#define K1 3072
#define N1 1024
#define NC 50

typedef float  f32x4  __attribute__((ext_vector_type(4)));
typedef short  short8 __attribute__((ext_vector_type(8)));

#define SA_STRIDE 40    // 32 + 8 pad (bf16 elems)
#define SH_STRIDE 136   // 128 + 8
#define SW_STRIDE 136

struct __align__(16) SmemT {
  union {
    struct { short A[128 * SA_STRIDE]; short BT[128 * SA_STRIDE]; } s;   // staging (20.5 KB)
    struct { short h[128 * SH_STRIDE]; short w2t[64 * SW_STRIDE]; } e;   // epilogue (52.2 KB)
  };
};

__device__ inline short f2bf(float f) {
  unsigned u = __builtin_bit_cast(unsigned, f);
  u += 0x7FFFu + ((u >> 16) & 1u);     // RNE
  return (short)(u >> 16);
}

__device__ inline short8 cvt8(float4 u, float4 v) {
  short8 r;
  r[0] = f2bf(u.x); r[1] = f2bf(u.y); r[2] = f2bf(u.z); r[3] = f2bf(u.w);
  r[4] = f2bf(v.x); r[5] = f2bf(v.y); r[6] = f2bf(v.z); r[7] = f2bf(v.w);
  return r;
}

__global__ __launch_bounds__(256, 2)
void hoi_fused(const float* __restrict__ X, const float* __restrict__ W1,
               const float* __restrict__ B1, const float* __restrict__ W2,
               const float* __restrict__ B2, float* __restrict__ OUT) {
  __shared__ SmemT sm;
  const int tid  = threadIdx.x;
  const int lane = tid & 63, wid = tid >> 6;
  const int wr = wid >> 1, wc = wid & 1;
  const int l15 = lane & 15, g = lane >> 4;
  const int bid = blockIdx.x;
  const int m_blk = bid >> 3, n_blk = bid & 7;
  const int m0 = m_blk * 128, n0 = n_blk * 128;

  // staging assignments
  const int arow = tid >> 1;            // 0..127
  const int akc  = (tid & 1) << 4;      // 0 / 16
  const float* aptr = X + (size_t)(m0 + arow) * K1 + akc;
  const int bk  = tid & 31;             // 0..31 (k within tile)
  const int bc0 = (tid >> 5) << 4;      // 0,16,...,112
  const float* bptr = W1 + (size_t)bk * N1 + n0 + bc0;

  f32x4 acc[4][4] = {};

  // preload tile 0
  float4 a0 = *(const float4*)(aptr + 0);
  float4 a1 = *(const float4*)(aptr + 4);
  float4 a2 = *(const float4*)(aptr + 8);
  float4 a3 = *(const float4*)(aptr + 12);
  float4 b0 = *(const float4*)(bptr + 0);
  float4 b1 = *(const float4*)(bptr + 4);
  float4 b2 = *(const float4*)(bptr + 8);
  float4 b3 = *(const float4*)(bptr + 12);

  for (int k0 = 0; k0 < K1; k0 += 32) {
    __syncthreads();   // previous iteration's LDS reads complete

    // write A tile: [row][k] bf16, padded
    *(short8*)&sm.s.A[arow * SA_STRIDE + akc + 0] = cvt8(a0, a1);
    *(short8*)&sm.s.A[arow * SA_STRIDE + akc + 8] = cvt8(a2, a3);
    // write B^T tile: [col][k] bf16, padded (16 scalar b16 writes)
    {
      float bb0[4] = {b0.x, b0.y, b0.z, b0.w};
      float bb1[4] = {b1.x, b1.y, b1.z, b1.w};
      float bb2[4] = {b2.x, b2.y, b2.z, b2.w};
      float bb3[4] = {b3.x, b3.y, b3.z, b3.w};
#pragma unroll
      for (int i = 0; i < 4; ++i) sm.s.BT[(bc0 + 0  + i) * SA_STRIDE + bk] = f2bf(bb0[i]);
#pragma unroll
      for (int i = 0; i < 4; ++i) sm.s.BT[(bc0 + 4  + i) * SA_STRIDE + bk] = f2bf(bb1[i]);
#pragma unroll
      for (int i = 0; i < 4; ++i) sm.s.BT[(bc0 + 8  + i) * SA_STRIDE + bk] = f2bf(bb2[i]);
#pragma unroll
      for (int i = 0; i < 4; ++i) sm.s.BT[(bc0 + 12 + i) * SA_STRIDE + bk] = f2bf(bb3[i]);
    }

    // issue next tile's global loads (overlap with barrier + MFMA below)
    if (k0 + 32 < K1) {
      a0 = *(const float4*)(aptr + k0 + 32 + 0);
      a1 = *(const float4*)(aptr + k0 + 32 + 4);
      a2 = *(const float4*)(aptr + k0 + 32 + 8);
      a3 = *(const float4*)(aptr + k0 + 32 + 12);
      const float* bp = bptr + (size_t)(k0 + 32) * N1;
      b0 = *(const float4*)(bp + 0);
      b1 = *(const float4*)(bp + 4);
      b2 = *(const float4*)(bp + 8);
      b3 = *(const float4*)(bp + 12);
    }

    __syncthreads();   // tile staged

    short8 af[4], bf_[4];
#pragma unroll
    for (int mt = 0; mt < 4; ++mt)
      af[mt] = *(const short8*)&sm.s.A[(wr * 64 + mt * 16 + l15) * SA_STRIDE + g * 8];
#pragma unroll
    for (int nt = 0; nt < 4; ++nt)
      bf_[nt] = *(const short8*)&sm.s.BT[(wc * 64 + nt * 16 + l15) * SA_STRIDE + g * 8];
#pragma unroll
    for (int mt = 0; mt < 4; ++mt)
#pragma unroll
      for (int nt = 0; nt < 4; ++nt)
        acc[mt][nt] = __builtin_amdgcn_mfma_f32_16x16x32_bf16(af[mt], bf_[nt], acc[mt][nt], 0, 0, 0);
  }

  __syncthreads();   // everyone done reading staging LDS; safe to alias

  // ---- epilogue: bias + relu -> h tile (bf16 in LDS) ----
  float b1v[4];
#pragma unroll
  for (int nt = 0; nt < 4; ++nt) b1v[nt] = B1[n0 + wc * 64 + nt * 16 + l15];
#pragma unroll
  for (int mt = 0; mt < 4; ++mt)
#pragma unroll
    for (int nt = 0; nt < 4; ++nt)
#pragma unroll
      for (int j = 0; j < 4; ++j) {
        int row = wr * 64 + mt * 16 + g * 4 + j;
        int col = wc * 64 + nt * 16 + l15;
        float v = acc[mt][nt][j] + b1v[nt];
        sm.e.h[row * SH_STRIDE + col] = f2bf(fmaxf(v, 0.f));
      }

  // ---- stage w2 slice, transposed: w2t[c][kk] = w2[n0+kk][c] ----
  {
    int kk = tid >> 1, c0 = (tid & 1) * 32;
#pragma unroll
    for (int i = 0; i < 32; ++i) {
      int c = c0 + i;
      float v = (c < NC) ? W2[(size_t)(n0 + kk) * NC + c] : 0.f;
      sm.e.w2t[c * SW_STRIDE + kk] = f2bf(v);
    }
  }
  __syncthreads();

  // ---- GEMM2: scores_partial[128][64] = h[128][128] * w2t^T ----
  f32x4 acc2[2][4] = {};
#pragma unroll
  for (int ks = 0; ks < 4; ++ks) {
    short8 a2f[2], b2f[4];
#pragma unroll
    for (int mt2 = 0; mt2 < 2; ++mt2)
      a2f[mt2] = *(const short8*)&sm.e.h[(wid * 32 + mt2 * 16 + l15) * SH_STRIDE + ks * 32 + g * 8];
#pragma unroll
    for (int nt2 = 0; nt2 < 4; ++nt2)
      b2f[nt2] = *(const short8*)&sm.e.w2t[(nt2 * 16 + l15) * SW_STRIDE + ks * 32 + g * 8];
#pragma unroll
    for (int mt2 = 0; mt2 < 2; ++mt2)
#pragma unroll
      for (int nt2 = 0; nt2 < 4; ++nt2)
        acc2[mt2][nt2] = __builtin_amdgcn_mfma_f32_16x16x32_bf16(a2f[mt2], b2f[nt2], acc2[mt2][nt2], 0, 0, 0);
  }

  // ---- atomic accumulate partial scores ----
#pragma unroll
  for (int mt2 = 0; mt2 < 2; ++mt2)
#pragma unroll
    for (int nt2 = 0; nt2 < 4; ++nt2) {
      int col = nt2 * 16 + l15;
      if (col < NC) {
#pragma unroll
        for (int j = 0; j < 4; ++j) {
          int row = wid * 32 + mt2 * 16 + g * 4 + j;
          float v = acc2[mt2][nt2][j];
          if (n_blk == 0) v += B2[col];
          atomicAdd(&OUT[(size_t)(m0 + row) * NC + col], v);
        }
      }
    }
}

extern "C" void kernel_launch(void* const* d_in, const int* in_sizes, int n_in,
                              void* d_out, int out_size, void* d_ws, size_t ws_size,
                              hipStream_t stream) {
  const float* X  = (const float*)d_in[0];
  const float* W1 = (const float*)d_in[1];
  const float* B1 = (const float*)d_in[2];
  const float* W2 = (const float*)d_in[3];
  const float* B2 = (const float*)d_in[4];
  float* OUT = (float*)d_out;

  hipMemsetAsync(d_out, 0, (size_t)out_size * sizeof(float), stream);
  hipLaunchKernelGGL(hoi_fused, dim3(2048), dim3(256), 0, stream, X, W1, B1, W2, B2, OUT);
}